// Round 3
// baseline (1606.171 us; speedup 1.0000x reference)
//
#include <hip/hip_runtime.h>
#include <stdint.h>
#include <math.h>

#define TT 1024
#define FF 32
#define HH 64
#define CSTR 176   // f16 per B-column (88 dwords: cols start at banks 0,24,16,8 -> uniform 2-way, free)

typedef unsigned int u32;
typedef _Float16 f16;
typedef __attribute__((ext_vector_type(8))) _Float16 half8;  // 8 fp16 = 4 VGPRs (MFMA A/B frag)
typedef __attribute__((ext_vector_type(4))) float v4f;       // MFMA C/D frag

// hardware-exp2/rcp nonlinearities (v_exp_f32 + v_rcp_f32, ~1e-6 abs err)
__device__ __forceinline__ float fsig(float x) {
    return __builtin_amdgcn_rcpf(1.f + __builtin_amdgcn_exp2f(-1.44269504088896341f * x));
}
__device__ __forceinline__ float ftanh(float x) {
    return 2.f * __builtin_amdgcn_rcpf(1.f + __builtin_amdgcn_exp2f(-2.88539008177792681f * x)) - 1.f;
}

// load 8 consecutive fp32 -> fp16 octet (RNE), for A-fragment prep
__device__ __forceinline__ half8 ld8h(const float* p) {
    float4 a = *(const float4*)p, b = *(const float4*)(p + 4);
    half8 r;
    r[0] = (f16)a.x; r[1] = (f16)a.y; r[2] = (f16)a.z; r[3] = (f16)a.w;
    r[4] = (f16)b.x; r[5] = (f16)b.y; r[6] = (f16)b.z; r[7] = (f16)b.w;
    return r;
}

// lane n <-> n^1 pair sum via DPP quad_perm [1,0,3,2]
__device__ __forceinline__ float pairsum(float v) {
    int t = __builtin_amdgcn_update_dpp(0, __float_as_int(v), 0xB1, 0xF, 0xF, true);
    return v + __int_as_float(t);
}

// Round-3 structure: TWO sequences per block through the idle MFMA columns.
//  - B cols (mod 4): col c = seq (c>>1)&1, hi/lo c&1. Same A (weights shared).
//    One 72-MFMA pass per step advances BOTH sequences.
//  - Grid 256 = 1 block/CU (round-robin over 8 XCDs -> 32/XCD -> 1/CU):
//    1 wave/SIMD, halving the issue-port contention measured at 91% in r2.
//  - Pair p=n>>1: seq p&1, slot p>>1. Chain-1 tile w*6+slot (all pairs);
//    chain-2 tile w*6+4+slot for slot<2. Lanes 12..15 (slot 3) also stage x.
//  - K layout per col: [h_enc(0..63) | x(64..95, hi cols only) | h_dec(96..127)].
//  - Everything else (hi/lo compensated fp16 h, DPP pair-reduce, one barrier,
//    deferred x prefetch) carried over from round 2.

__global__ __launch_bounds__(256, 1)
void lstm_ae_mfma(const float* __restrict__ x,
                  const float* __restrict__ ewih, const float* __restrict__ ewhh,
                  const float* __restrict__ ebih, const float* __restrict__ ebhh,
                  const float* __restrict__ dwih, const float* __restrict__ dwhh,
                  const float* __restrict__ dbih, const float* __restrict__ dbhh,
                  float* __restrict__ out)
{
    const int b2 = blockIdx.x;          // sequences 2*b2, 2*b2+1
    const int t = threadIdx.x;
    const int w = t >> 6;               // wave 0..3
    const int l = t & 63;
    const int q = l >> 4;               // quad: A/B k-group, D row-group
    const int n = l & 15;               // A row-in-tile / B+D column

    __shared__ __align__(16) f16 Bst[2][4][CSTR];    // [buf][col][K+pad]
    __shared__ __align__(16) float xst[2][2][2048];  // [seq][chunk parity][64 steps x 32]

    // ---- persistent A fragments (fp32 -> fp16): lane holds A[m=n][k=q*8+j] ----
    half8 af[6][3];
#pragma unroll
    for (int i = 0; i < 6; ++i) {
        int tile = w * 6 + i;
        if (tile < 16) {
            int r = (n & 3) * 64 + tile * 4 + (n >> 2);          // enc W row
            af[i][0] = ld8h(ewhh + r * 64 + q * 8);              // k 0..31  (h_enc)
            af[i][1] = ld8h(ewhh + r * 64 + 32 + q * 8);         // k 32..63 (h_enc)
            af[i][2] = ld8h(ewih + r * 32 + q * 8);              // k 64..95 (x)
        } else {
            int r = (n & 3) * 32 + (tile - 16) * 4 + (n >> 2);   // dec V row
            af[i][0] = ld8h(dwih + r * 64 + q * 8);              // k 0..31  (h_enc)
            af[i][1] = ld8h(dwih + r * 64 + 32 + q * 8);         // k 32..63 (h_enc)
            af[i][2] = ld8h(dwhh + r * 32 + q * 8);              // k 96..127 (h_dec)
        }
    }

    // ---- lane roles ----
    const int pr   = n >> 1;            // pair 0..7
    const int sq   = pr & 1;            // sequence within block
    const int slot = pr >> 1;           // 0..3
    const int T1   = w * 6 + slot;                  // chain-1 tile
    const bool e1  = (T1 < 16);
    const int u1i  = e1 ? T1 * 4 + q : (T1 - 16) * 4 + q;
    const bool has2 = (slot < 2);
    const int T2   = w * 6 + 4 + slot;              // chain-2 tile (slot<2)
    const bool e2  = (T2 < 16);
    const int u2i  = e2 ? T2 * 4 + q : (T2 - 16) * 4 + q;

    // precomputed LDS write offsets for h (hi col if n even, lo col if n odd)
    const int wk1 = (sq * 2 + (n & 1)) * CSTR + (e1 ? u1i : 96 + u1i);
    const int wk2 = (sq * 2 + (n & 1)) * CSTR + (e2 ? u2i : 96 + u2i);

    // ---- biases + cell states ----
    float b10 = 0.f, b11 = 0.f, b12 = 0.f, b13 = 0.f, c1 = 0.f;
    float b20 = 0.f, b21 = 0.f, b22 = 0.f, b23 = 0.f, c2 = 0.f;
    if (e1) {
        b10 = ebih[u1i]       + ebhh[u1i];
        b11 = ebih[64 + u1i]  + ebhh[64 + u1i];
        b12 = ebih[128 + u1i] + ebhh[128 + u1i];
        b13 = ebih[192 + u1i] + ebhh[192 + u1i];
    } else {
        b10 = dbih[u1i]      + dbhh[u1i];
        b11 = dbih[32 + u1i] + dbhh[32 + u1i];
        b12 = dbih[64 + u1i] + dbhh[64 + u1i];
        b13 = dbih[96 + u1i] + dbhh[96 + u1i];
    }
    if (has2) {
        if (e2) {
            b20 = ebih[u2i]       + ebhh[u2i];
            b21 = ebih[64 + u2i]  + ebhh[64 + u2i];
            b22 = ebih[128 + u2i] + ebhh[128 + u2i];
            b23 = ebih[192 + u2i] + ebhh[192 + u2i];
        } else {
            b20 = dbih[u2i]      + dbhh[u2i];
            b21 = dbih[32 + u2i] + dbhh[32 + u2i];
            b22 = dbih[64 + u2i] + dbhh[64 + u2i];
            b23 = dbih[96 + u2i] + dbhh[96 + u2i];
        }
    }

    // ---- prologue: zero Bst, stage x chunk 0 (both seqs), x[0] into buf0 ----
    { u32* bz = (u32*)&Bst[0][0][0]; for (int i2 = t; i2 < 2 * 4 * CSTR / 2; i2 += 256) bz[i2] = 0u; }
    const float* xb0 = x + (size_t)(2 * b2) * TT * FF;
    const float* xb1 = xb0 + TT * FF;
    *(float4*)&xst[0][0][t * 8]     = *(const float4*)(xb0 + t * 8);
    *(float4*)&xst[0][0][t * 8 + 4] = *(const float4*)(xb0 + t * 8 + 4);
    *(float4*)&xst[1][0][t * 8]     = *(const float4*)(xb1 + t * 8);
    *(float4*)&xst[1][0][t * 8 + 4] = *(const float4*)(xb1 + t * 8 + 4);
    __syncthreads();
    if (t < 32)       Bst[0][0][64 + t]        = (f16)xst[0][0][t];
    else if (t < 64)  Bst[0][2][64 + (t - 32)] = (f16)xst[1][0][t - 32];
    __syncthreads();

    float* outp = out + (size_t)(2 * b2 + sq) * TT * FF;

    for (int tt = 0; tt <= TT; ++tt) {
        const int p = tt & 1;

        // x chunk prefetch: issue global loads now, LDS write deferred to loop end
        float4 pa0, pa1, pb0, pb1;
        const int cn = (tt >> 6) + 1;
        const bool pf = ((tt & 63) == 0) && (cn < 16);
        if (pf) {
            pa0 = *(const float4*)(xb0 + cn * 2048 + t * 8);
            pa1 = *(const float4*)(xb0 + cn * 2048 + t * 8 + 4);
            pb0 = *(const float4*)(xb1 + cn * 2048 + t * 8);
            pb1 = *(const float4*)(xb1 + cn * 2048 + t * 8 + 4);
        }

        // ---- B fragments: col = n&3 (4 lanes/address broadcast) ----
        const f16* Bp = &Bst[p][0][0];
        const int cb = (n & 3) * CSTR + q * 8;
        half8 bf0 = *(const half8*)(Bp + cb);
        half8 bf1 = *(const half8*)(Bp + cb + 32);
        half8 bf2 = *(const half8*)(Bp + cb + 64);
        half8 bf3 = *(const half8*)(Bp + cb + 96);

        v4f zero = {0.f, 0.f, 0.f, 0.f};
        v4f acc[6];
#pragma unroll
        for (int i = 0; i < 6; ++i)
            acc[i] = __builtin_amdgcn_mfma_f32_16x16x32_f16(af[i][2], (w * 6 + i < 16) ? bf2 : bf3,
                                                            zero, 0, 0, 0);
#pragma unroll
        for (int i = 0; i < 6; ++i)
            acc[i] = __builtin_amdgcn_mfma_f32_16x16x32_f16(af[i][0], bf0, acc[i], 0, 0, 0);
#pragma unroll
        for (int i = 0; i < 6; ++i)
            acc[i] = __builtin_amdgcn_mfma_f32_16x16x32_f16(af[i][1], bf1, acc[i], 0, 0, 0);

        // ---- select owned tiles (cndmask trees, static indices) ----
        v4f u1 = acc[0];
        if (slot == 1) u1 = acc[1];
        if (slot == 2) u1 = acc[2];
        if (slot == 3) u1 = acc[3];
        v4f u2 = acc[4];
        if (slot == 1) u2 = acc[5];

        // ---- hi+lo pair reduce (pure VALU) ----
        v4f s1, s2;
#pragma unroll
        for (int e = 0; e < 4; ++e) { s1[e] = pairsum(u1[e]); s2[e] = pairsum(u2[e]); }

        f16* Bw = &Bst[p ^ 1][0][0];

        // ---- chain 1 unit update ----
        if (e1 ? (tt < TT) : (tt >= 1)) {
            float i_ = fsig(s1[0] + b10);
            float f_ = fsig(s1[1] + b11);
            float g_ = ftanh(s1[2] + b12);
            float o_ = fsig(s1[3] + b13);
            c1 = f_ * c1 + i_ * g_;
            float h = o_ * ftanh(c1);
            f16 hi = (f16)h;
            f16 lo = (f16)(h - (float)hi);
            Bw[wk1] = (n & 1) ? lo : hi;
            if (!e1 && !(n & 1)) outp[(size_t)(tt - 1) * FF + u1i] = h;
        }
        // ---- chain 2 unit update (pairs 0..3) ----
        if (has2 && (e2 ? (tt < TT) : (tt >= 1))) {
            float i_ = fsig(s2[0] + b20);
            float f_ = fsig(s2[1] + b21);
            float g_ = ftanh(s2[2] + b22);
            float o_ = fsig(s2[3] + b23);
            c2 = f_ * c2 + i_ * g_;
            float h = o_ * ftanh(c2);
            f16 hi = (f16)h;
            f16 lo = (f16)(h - (float)hi);
            Bw[wk2] = (n & 1) ? lo : hi;
            if (!e2 && !(n & 1)) outp[(size_t)(tt - 1) * FF + u2i] = h;
        }
        // ---- x staging for enc step tt+1 (lanes 12..15, both seqs' hi cols) ----
        if (n >= 12) {
            int st = tt + 1;
            if (st < TT) {
                int idx = n - 12;               // 0..3
                int sx = idx >> 1;              // seq
                int jj = w * 8 + q * 2 + (idx & 1);
                Bw[(sx * 2) * CSTR + 64 + jj] = (f16)xst[sx][(st >> 6) & 1][(st & 63) * 32 + jj];
            }
        }

        // deferred x-chunk prefetch write (loads in flight across MFMA + update)
        if (pf) {
            *(float4*)&xst[0][cn & 1][t * 8]     = pa0;
            *(float4*)&xst[0][cn & 1][t * 8 + 4] = pa1;
            *(float4*)&xst[1][cn & 1][t * 8]     = pb0;
            *(float4*)&xst[1][cn & 1][t * 8 + 4] = pb1;
        }

        __syncthreads();   // the only barrier per step
    }
}

extern "C" void kernel_launch(void* const* d_in, const int* in_sizes, int n_in,
                              void* d_out, int out_size, void* d_ws, size_t ws_size,
                              hipStream_t stream) {
    (void)in_sizes; (void)n_in; (void)out_size; (void)d_ws; (void)ws_size;
    lstm_ae_mfma<<<256, 256, 0, stream>>>((const float*)d_in[0],
                                          (const float*)d_in[1], (const float*)d_in[2],
                                          (const float*)d_in[3], (const float*)d_in[4],
                                          (const float*)d_in[5], (const float*)d_in[6],
                                          (const float*)d_in[7], (const float*)d_in[8],
                                          (float*)d_out);
}

// Round 4
// 741.359 us; speedup vs baseline: 2.1665x; 2.1665x over previous
//
#include <hip/hip_runtime.h>
#include <stdint.h>
#include <math.h>

#define TT 1024
#define FF 32
#define HH 64

typedef unsigned int u32;
typedef _Float16 f16;
typedef __attribute__((ext_vector_type(8))) _Float16 half8;  // 8 fp16 = 4 VGPRs (MFMA A/B frag)
typedef __attribute__((ext_vector_type(4))) float v4f;       // MFMA C/D frag

// hardware-exp2/rcp nonlinearities (v_exp_f32 + v_rcp_f32, ~1e-6 abs err)
__device__ __forceinline__ float fsig(float x) {
    return __builtin_amdgcn_rcpf(1.f + __builtin_amdgcn_exp2f(-1.44269504088896341f * x));
}
__device__ __forceinline__ float ftanh(float x) {
    return 2.f * __builtin_amdgcn_rcpf(1.f + __builtin_amdgcn_exp2f(-2.88539008177792681f * x)) - 1.f;
}

// load 8 consecutive fp32 -> fp16 octet (RNE), for A-fragment prep
__device__ __forceinline__ half8 ld8h(const float* p) {
    float4 a = *(const float4*)p, b = *(const float4*)(p + 4);
    half8 r;
    r[0] = (f16)a.x; r[1] = (f16)a.y; r[2] = (f16)a.z; r[3] = (f16)a.w;
    r[4] = (f16)b.x; r[5] = (f16)b.y; r[6] = (f16)b.z; r[7] = (f16)b.w;
    return r;
}

// Round-4 = round-2 (741 us, 512 blocks x 256 thr, 2 blocks/CU) + ONE change:
// the per-step __syncthreads() is replaced by a raw s_barrier preceded by an
// lgkmcnt(0)-only wait. __syncthreads makes the compiler emit
// s_waitcnt vmcnt(0) before s_barrier, which drains the per-step global
// out[] store (~300-600 cy of HBM write-ack) INSIDE the serial recurrence,
// every step. Stores are write-only fire-and-forget here: only LDS writes
// need to be visible across the barrier, so lgkmcnt(0) suffices; the out[]
// stores stay in flight across steps (T4 counted-vmcnt discipline).
// Round-3's 2-seq/1-block-per-CU experiment is reverted: at 1 wave/SIMD the
// exposed per-step path doubled (1735 -> 3760 cy) -- 2 independent blocks/CU
// is the occupancy this latency regime needs.

__global__ __launch_bounds__(256, 2)
void lstm_ae_mfma(const float* __restrict__ x,
                  const float* __restrict__ ewih, const float* __restrict__ ewhh,
                  const float* __restrict__ ebih, const float* __restrict__ ebhh,
                  const float* __restrict__ dwih, const float* __restrict__ dwhh,
                  const float* __restrict__ dbih, const float* __restrict__ dbhh,
                  float* __restrict__ out)
{
    const int b = blockIdx.x;
    const int t = threadIdx.x;
    const int w = t >> 6;        // wave 0..3
    const int l = t & 63;
    const int q = l >> 4;        // quad: A/B k-group, D row-group
    const int n = l & 15;        // A row-in-tile / B+D column

    __shared__ __align__(16) f16 Bst[2][2][160];     // [buf][col hi/lo][K(128)+pad]
    __shared__ __align__(16) float xst[2][2048];     // x 64-step chunks, fp32, dbuf

    // ---- persistent A fragments (fp32 -> fp16): lane holds A[m=n][k=q*8+j] ----
    half8 af[6][3];
#pragma unroll
    for (int i = 0; i < 6; ++i) {
        int tile = w * 6 + i;
        if (tile < 16) {
            int r = (n & 3) * 64 + tile * 4 + (n >> 2);          // enc W row
            af[i][0] = ld8h(ewhh + r * 64 + q * 8);              // k 0..31  (h_enc)
            af[i][1] = ld8h(ewhh + r * 64 + 32 + q * 8);         // k 32..63 (h_enc)
            af[i][2] = ld8h(ewih + r * 32 + q * 8);              // k 64..95 (x)
        } else {
            int r = (n & 3) * 32 + (tile - 16) * 4 + (n >> 2);   // dec V row
            af[i][0] = ld8h(dwih + r * 64 + q * 8);              // k 0..31  (h_enc)
            af[i][1] = ld8h(dwih + r * 64 + 32 + q * 8);         // k 32..63 (h_enc)
            af[i][2] = ld8h(dwhh + r * 32 + q * 8);              // k 96..127 (h_dec)
        }
    }

    // ---- lane-pair roles: pair s=n>>1 (<6) owns tile w*6+s; even=hi, odd=lo ----
    const int sel = n >> 1;                          // 0..7
    const bool act = (n < 12);                       // 6 pairs active
    const int tile_s = w * 6 + (sel < 6 ? sel : 0);  // clamped for inactive lanes
    const bool is_enc = (tile_s < 16);
    const int u = is_enc ? (tile_s * 4 + q) : ((tile_s - 16) * 4 + q);

    float b0 = 0.f, b1 = 0.f, b2 = 0.f, b3 = 0.f, c_st = 0.f;
    if (act) {
        if (is_enc) {
            b0 = ebih[u]       + ebhh[u];
            b1 = ebih[64 + u]  + ebhh[64 + u];
            b2 = ebih[128 + u] + ebhh[128 + u];
            b3 = ebih[192 + u] + ebhh[192 + u];
        } else {
            b0 = dbih[u]      + dbhh[u];
            b1 = dbih[32 + u] + dbhh[32 + u];
            b2 = dbih[64 + u] + dbhh[64 + u];
            b3 = dbih[96 + u] + dbhh[96 + u];
        }
    }

    // ---- prologue: zero both Bst buffers, stage x chunk 0, x[0] into buf0 ----
    { u32* bz = (u32*)&Bst[0][0][0]; for (int i2 = t; i2 < 2 * 2 * 160 / 2; i2 += 256) bz[i2] = 0u; }
    const float* xb = x + (size_t)b * TT * FF;
    *(float4*)&xst[0][t * 8]     = *(const float4*)(xb + t * 8);
    *(float4*)&xst[0][t * 8 + 4] = *(const float4*)(xb + t * 8 + 4);
    __syncthreads();
    if (t >= 96 && t < 128) Bst[0][0][64 + (t - 96)] = (f16)xst[0][t - 96];
    __syncthreads();

    for (int tt = 0; tt <= TT; ++tt) {
        const int p = tt & 1;

        // x chunk prefetch: issue loads now, write LDS just before the barrier
        float4 px0, px1;
        const int cn = (tt >> 6) + 1;
        const bool pf = ((tt & 63) == 0) && (cn < 16);
        if (pf) {
            px0 = *(const float4*)(xb + cn * 2048 + t * 8);
            px1 = *(const float4*)(xb + cn * 2048 + t * 8 + 4);
        }

        // ---- B fragments (col = n&1 replicated, broadcast reads) ----
        const f16* Bp = &Bst[p][0][0];
        const int cb = (n & 1) * 160 + q * 8;
        half8 bf0 = *(const half8*)(Bp + cb);
        half8 bf1 = *(const half8*)(Bp + cb + 32);
        half8 bf2 = *(const half8*)(Bp + cb + 64);
        half8 bf3 = *(const half8*)(Bp + cb + 96);

        v4f zero = {0.f, 0.f, 0.f, 0.f};
        v4f acc[6];
#pragma unroll
        for (int i = 0; i < 6; ++i)
            acc[i] = __builtin_amdgcn_mfma_f32_16x16x32_f16(af[i][2], (w * 6 + i < 16) ? bf2 : bf3,
                                                            zero, 0, 0, 0);
#pragma unroll
        for (int i = 0; i < 6; ++i)
            acc[i] = __builtin_amdgcn_mfma_f32_16x16x32_f16(af[i][0], bf0, acc[i], 0, 0, 0);
#pragma unroll
        for (int i = 0; i < 6; ++i)
            acc[i] = __builtin_amdgcn_mfma_f32_16x16x32_f16(af[i][1], bf1, acc[i], 0, 0, 0);

        // ---- select this pair's tile (cndmask chain, static indices) ----
        v4f u_ = acc[0];
#pragma unroll
        for (int i = 1; i < 6; ++i) if (sel == i) u_ = acc[i];

        // ---- hi+lo reduce: lane n <-> n^1 via DPP quad_perm [1,0,3,2] ----
        v4f s_;
#pragma unroll
        for (int e = 0; e < 4; ++e) {
            int tmp = __builtin_amdgcn_update_dpp(0, __float_as_int(u_[e]), 0xB1, 0xF, 0xF, true);
            s_[e] = u_[e] + __int_as_float(tmp);
        }

        // ---- unit update (both lanes of pair, redundant) + h write to buf p^1 ----
        f16* Bw = &Bst[p ^ 1][0][0];
        if (act && (is_enc ? (tt < TT) : (tt >= 1))) {
            float i_ = fsig(s_[0] + b0);
            float f_ = fsig(s_[1] + b1);
            float g_ = ftanh(s_[2] + b2);
            float o_ = fsig(s_[3] + b3);
            c_st = f_ * c_st + i_ * g_;
            float h = o_ * ftanh(c_st);
            f16 hi = (f16)h;
            f16 lo = (f16)(h - (float)hi);
            const int kk = is_enc ? u : (96 + u);
            Bw[(n & 1) * 160 + kk] = (n & 1) ? lo : hi;
            if (!is_enc && !(n & 1))
                out[(size_t)b * TT * FF + (size_t)(tt - 1) * FF + u] = h;
        } else if (n == 12 || n == 13) {        // stage x for enc step tt+1
            int st = tt + 1;
            if (st < TT) {
                int j = w * 8 + q * 2 + (n - 12);
                Bw[64 + j] = (f16)xst[(st >> 6) & 1][(st & 63) * 32 + j];
            }
        }

        // deferred x-chunk prefetch write (loads in flight across MFMA + update)
        if (pf) {
            *(float4*)&xst[cn & 1][t * 8]     = px0;
            *(float4*)&xst[cn & 1][t * 8 + 4] = px1;
        }

        // ---- raw barrier: drain LDS only; out[] stores stay in flight ----
        asm volatile("s_waitcnt lgkmcnt(0)" ::: "memory");
        __builtin_amdgcn_s_barrier();
        __builtin_amdgcn_sched_barrier(0);
    }
}

extern "C" void kernel_launch(void* const* d_in, const int* in_sizes, int n_in,
                              void* d_out, int out_size, void* d_ws, size_t ws_size,
                              hipStream_t stream) {
    (void)in_sizes; (void)n_in; (void)out_size; (void)d_ws; (void)ws_size;
    lstm_ae_mfma<<<512, 256, 0, stream>>>((const float*)d_in[0],
                                          (const float*)d_in[1], (const float*)d_in[2],
                                          (const float*)d_in[3], (const float*)d_in[4],
                                          (const float*)d_in[5], (const float*)d_in[6],
                                          (const float*)d_in[7], (const float*)d_in[8],
                                          (float*)d_out);
}